// Round 6
// baseline (477.859 us; speedup 1.0000x reference)
//
#include <hip/hip_runtime.h>
#include <math.h>

#define FEAT  128
#define INTER 512
#define EMB   512
#define TB    32
#define SUBP  520   // u16 stride per kt-subplane of sXn (pad: +4-bank shift per kt)

typedef short s16x8 __attribute__((ext_vector_type(8)));
typedef float f32x4 __attribute__((ext_vector_type(4)));

static constexpr float F_EPS    = 1e-6f;
static constexpr float F_LN_EPS = 1e-5f;

#define MFMA(a,b,c) __builtin_amdgcn_mfma_f32_16x16x32_bf16(a,b,c,0,0,0)

// u16-element offsets inside wsP (total 2 MB)
#define W1BASE 0                 // 128 frags * 1536 u16 (hi|mid|lo, 512 each)
#define W2BASE 196608            // 512 frags * 1536 u16
#define EBASE  983040            // 64  frags * 1024 u16 (hi|lo)

__device__ __forceinline__ unsigned short f2bf(float f) {
    union { float f; unsigned u; } v; v.f = f;
    unsigned r = v.u + 0x7FFFu + ((v.u >> 16) & 1u);
    return (unsigned short)(r >> 16);
}
__device__ __forceinline__ float bf2f(unsigned short h) {
    union { unsigned u; float f; } v; v.u = ((unsigned)h) << 16;
    return v.f;
}
__device__ __forceinline__ void split3(float x, unsigned short& h,
                                       unsigned short& m, unsigned short& l) {
    h = f2bf(x);
    float r1 = x - bf2f(h);
    m = f2bf(r1);
    l = f2bf(r1 - bf2f(m));
}
__device__ __forceinline__ float gelu_exact(float v) {
    return 0.5f * v * (1.0f + erff(v * 0.70710678118654752440f));
}

// Pack w1/w2 into 3-split, emb into 2-split MFMA B-fragments.
// Frag lane l holds B[k = kt*32 + 8*(l>>4) + i][n = nt*16 + (l&15)], i=0..7.
__global__ __launch_bounds__(256) void vc_pack(const float* __restrict__ w1,
                                               const float* __restrict__ w2,
                                               const float* __restrict__ emb,
                                               unsigned short* __restrict__ P) {
    int id = blockIdx.x * 256 + threadIdx.x;
    int fid = id >> 6, l = id & 63;
    if (fid >= 704) return;
    int lr = l & 15, lq = l >> 4;
    float v[8];
    size_t dst;
    int three = 1;
    if (fid < 128) {
        int kt = fid >> 5, nt = fid & 31;
        const float* s = w1 + (size_t)(nt * 16 + lr) * FEAT + kt * 32 + 8 * lq;
        #pragma unroll
        for (int i = 0; i < 8; ++i) v[i] = s[i];
        dst = W1BASE + (size_t)fid * 1536;
    } else if (fid < 640) {
        int f2 = fid - 128, kt = f2 >> 5, nt = f2 & 31;
        const float* s = w2 + (size_t)(nt * 16 + lr) * INTER + kt * 32 + 8 * lq;
        #pragma unroll
        for (int i = 0; i < 8; ++i) v[i] = s[i];
        dst = W2BASE + (size_t)f2 * 1536;
    } else {
        int f3 = fid - 640, kt = f3 >> 3, nt = f3 & 7;
        #pragma unroll
        for (int i = 0; i < 8; ++i)
            v[i] = emb[(size_t)(kt * 32 + 8 * lq + i) * FEAT + nt * 16 + lr];
        dst = EBASE + (size_t)f3 * 1024;
        three = 0;
    }
    s16x8 vh, vm, vl;
    #pragma unroll
    for (int i = 0; i < 8; ++i) {
        unsigned short a, b, c;
        split3(v[i], a, b, c);
        vh[i] = (short)a; vm[i] = (short)b; vl[i] = (short)c;
    }
    *(s16x8*)(P + dst + l * 8)       = vh;
    *(s16x8*)(P + dst + 512 + l * 8) = vm;   // for emb this is the lo plane
    if (three) *(s16x8*)(P + dst + 1024 + l * 8) = vl;
}

__global__ __launch_bounds__(1024, 8) void vc_fused(
    const float* __restrict__ x,   const float* __restrict__ gu,
    const float* __restrict__ lnw, const float* __restrict__ lnb,
    const float* __restrict__ b1,  const float* __restrict__ b2,
    const float* __restrict__ scl, const unsigned short* __restrict__ wsP,
    float* __restrict__ out)
{
    // LDS map, 79488 B total -> 2 blocks/CU, 8 waves/SIMD:
    //  [0,      24960)  xn 3 planes of [2mt*4kt (stride 520)][64 slot][8] u16
    //  [24960,  74112)  h  3 planes of [32][256] u16, 16B-granule XOR swizzle
    //  [74112,  78208)  sC [32][32] u32 (code bytes, col-swizzled)
    //  [78208,  79488)  sPre[32] | sPart[8][32] | sFac[32]
    __shared__ __align__(16) unsigned char smem[79488];
    unsigned short* sXn = (unsigned short*)smem;
    unsigned short* sH  = (unsigned short*)(smem + 24960);
    unsigned*       sC  = (unsigned*)(smem + 74112);
    float*          sPre  = (float*)(smem + 78208);
    float*          sPart = (float*)(smem + 78336);
    float*          sFac  = (float*)(smem + 79360);

    const int tid = threadIdx.x;
    const int w  = tid >> 6;           // wave 0..15
    const int l  = tid & 63;
    const int lr = l & 15, lq = l >> 4;
    const long tok0 = (long)blockIdx.x * TB;

    // ---------------- prologue: issue gumbel-u loads early (16/thread) -------
    // index: flat gi = m*8 + ntl*4 + r  ->  u[(tok0+m*16+4lq+r)*512 + w*32+ntl*16+lr]
    float uv[16];
    #pragma unroll
    for (int m = 0; m < 2; ++m)
        #pragma unroll
        for (int ntl = 0; ntl < 2; ++ntl)
            #pragma unroll
            for (int r = 0; r < 4; ++r)
                uv[m * 8 + ntl * 4 + r] =
                    gu[(tok0 + m * 16 + 4 * lq + r) * 512L + w * 32 + ntl * 16 + lr];

    // ---------------- phase 0: scale, unit-norm, LayerNorm, 3-split frags ----
    if (tid < 512) {                   // waves 0..7; branch is wave-uniform
        const int t = tid >> 4;        // token 0..31
        const int q = tid & 15;        // feat octet 0..15
        const float* xr = x + (tok0 + t) * FEAT + q * 8;
        float v[8];
        #pragma unroll
        for (int k = 0; k < 8; ++k) v[k] = xr[k] / (scl[q * 8 + k] + F_EPS);
        float ss = 0.f;
        #pragma unroll
        for (int k = 0; k < 8; ++k) ss += v[k] * v[k];
        ss += __shfl_xor(ss, 1); ss += __shfl_xor(ss, 2);
        ss += __shfl_xor(ss, 4); ss += __shfl_xor(ss, 8);
        const float pre = sqrtf(ss);
        if (q == 0) sPre[t] = pre;
        const float ip = 1.0f / (pre + F_EPS);
        #pragma unroll
        for (int k = 0; k < 8; ++k) v[k] *= ip;
        float sm = 0.f;
        #pragma unroll
        for (int k = 0; k < 8; ++k) sm += v[k];
        sm += __shfl_xor(sm, 1); sm += __shfl_xor(sm, 2);
        sm += __shfl_xor(sm, 4); sm += __shfl_xor(sm, 8);
        const float mu = sm * (1.0f / 128.0f);
        float vv = 0.f;
        #pragma unroll
        for (int k = 0; k < 8; ++k) { float d = v[k] - mu; vv += d * d; }
        vv += __shfl_xor(vv, 1); vv += __shfl_xor(vv, 2);
        vv += __shfl_xor(vv, 4); vv += __shfl_xor(vv, 8);
        const float rst = 1.0f / sqrtf(vv * (1.0f / 128.0f) + F_LN_EPS);

        const int mt  = t >> 4;
        const int kt  = q >> 2;
        const int sub = q & 3;
        const size_t base = (size_t)(mt * 4 + kt) * SUBP
                          + (size_t)((t & 15) + 16 * sub) * 8;
        s16x8 vh, vm, vlo;
        #pragma unroll
        for (int i = 0; i < 8; ++i) {
            const float xnv = (v[i] - mu) * rst * lnw[q * 8 + i] + lnb[q * 8 + i];
            unsigned short a, b, c;
            split3(xnv, a, b, c);
            vh[i] = (short)a; vm[i] = (short)b; vlo[i] = (short)c;
        }
        *(s16x8*)(sXn + base)        = vh;
        *(s16x8*)(sXn + 4160 + base) = vm;
        *(s16x8*)(sXn + 8320 + base) = vlo;
    }
    __syncthreads();

    float gv[16];
    f32x4 acc2[2][2];
    #pragma unroll
    for (int m = 0; m < 2; ++m)
        #pragma unroll
        for (int n = 0; n < 2; ++n)
            #pragma unroll
            for (int r = 0; r < 4; ++r) acc2[m][n][r] = 0.f;

    for (int half = 0; half < 2; ++half) {
        // -------- GEMM1 over n-half: 1 n-tile/wave, 6-term split-bf16 --------
        // Gumbel g precompute is interleaved here (half 0 only): 4 logf-pairs
        // per kt iteration fill the MFMA shadow.
        f32x4 acc1[2];
        #pragma unroll
        for (int m = 0; m < 2; ++m)
            #pragma unroll
            for (int r = 0; r < 4; ++r) acc1[m][r] = 0.f;

        #pragma unroll
        for (int kt = 0; kt < 4; ++kt) {
            s16x8 A[2][3];
            #pragma unroll
            for (int m = 0; m < 2; ++m) {
                const size_t base = (size_t)(m * 4 + kt) * SUBP + (size_t)l * 8;
                A[m][0] = *(const s16x8*)(sXn + base);
                A[m][1] = *(const s16x8*)(sXn + 4160 + base);
                A[m][2] = *(const s16x8*)(sXn + 8320 + base);
            }
            if (half == 0) {
                #pragma unroll
                for (int j = 0; j < 4; ++j) {
                    const int gi = kt * 4 + j;
                    gv[gi] = 0.0f - logf(0.0f - logf(uv[gi]));
                }
            }
            const int nt = half * 16 + w;
            const unsigned short* bp = wsP + W1BASE + (size_t)(kt * 32 + nt) * 1536 + l * 8;
            const s16x8 bh = *(const s16x8*)bp;
            const s16x8 bm = *(const s16x8*)(bp + 512);
            const s16x8 bl = *(const s16x8*)(bp + 1024);
            #pragma unroll
            for (int m = 0; m < 2; ++m) {
                f32x4 c = acc1[m];
                c = MFMA(A[m][1], bm, c);    // mid*mid   (~2^-18)
                c = MFMA(A[m][2], bh, c);    // lo*hi     (~2^-18)
                c = MFMA(A[m][0], bl, c);    // hi*lo     (~2^-18)
                c = MFMA(A[m][1], bh, c);    // mid*hi    (~2^-9)
                c = MFMA(A[m][0], bm, c);    // hi*mid    (~2^-9)
                c = MFMA(A[m][0], bh, c);    // hi*hi
                acc1[m] = c;
            }
        }

        // -------- bias + gelu, 3-split, write h half --------
        {
            const float b1v = b1[half * 256 + w * 16 + lr];
            #pragma unroll
            for (int m = 0; m < 2; ++m)
                #pragma unroll
                for (int r = 0; r < 4; ++r) {
                    const float h = gelu_exact(acc1[m][r] + b1v);
                    unsigned short hh, hm, hl;
                    split3(h, hh, hm, hl);
                    const int tokr = 4 * lq + r;
                    const int row  = m * 16 + tokr;
                    const int nl   = w * 16 + lr;                  // 0..255
                    const int gsw  = (nl >> 3) ^ (tokr & 7);
                    const size_t off = (size_t)row * 256 + gsw * 8 + (nl & 7);
                    sH[off]          = hh;
                    sH[8192 + off]   = hm;
                    sH[16384 + off]  = hl;
                }
        }
        __syncthreads();

        // -------- GEMM2 partial over k-half: 8 k-tiles, 2 n-tiles/wave --------
        for (int kk = 0; kk < 8; ++kk) {
            s16x8 A[2][3];
            #pragma unroll
            for (int m = 0; m < 2; ++m) {
                const int row = m * 16 + lr;
                const int gsw = (kk * 4 + lq) ^ (lr & 7);
                const size_t off = (size_t)row * 256 + (size_t)gsw * 8;
                A[m][0] = *(const s16x8*)(sH + off);
                A[m][1] = *(const s16x8*)(sH + 8192 + off);
                A[m][2] = *(const s16x8*)(sH + 16384 + off);
            }
            __builtin_amdgcn_s_setprio(1);
            #pragma unroll
            for (int ntl = 0; ntl < 2; ++ntl) {
                const int fid2 = (half * 8 + kk) * 32 + (w * 2 + ntl);
                const unsigned short* bp = wsP + W2BASE + (size_t)fid2 * 1536 + l * 8;
                const s16x8 bh = *(const s16x8*)bp;
                const s16x8 bm = *(const s16x8*)(bp + 512);
                const s16x8 bl = *(const s16x8*)(bp + 1024);
                #pragma unroll
                for (int m = 0; m < 2; ++m) {
                    f32x4 c = acc2[m][ntl];
                    c = MFMA(A[m][1], bm, c);
                    c = MFMA(A[m][2], bh, c);
                    c = MFMA(A[m][0], bl, c);
                    c = MFMA(A[m][1], bh, c);
                    c = MFMA(A[m][0], bm, c);
                    c = MFMA(A[m][0], bh, c);
                    acc2[m][ntl] = c;
                }
            }
            __builtin_amdgcn_s_setprio(0);
        }
        __syncthreads();
    }

    // ---------------- phase 4: bias + precomputed gumbel + quad argmax -------
    {
        float b2v[2];
        #pragma unroll
        for (int ntl = 0; ntl < 2; ++ntl) b2v[ntl] = b2[w * 32 + ntl * 16 + lr];
        const int qq  = lr >> 2;
        const int cls = l & 3;
        #pragma unroll
        for (int m = 0; m < 2; ++m)
            #pragma unroll
            for (int ntl = 0; ntl < 2; ++ntl) {
                #pragma unroll
                for (int r = 0; r < 4; ++r) {
                    float v = acc2[m][ntl][r] + b2v[ntl] + gv[m * 8 + ntl * 4 + r];
                    int   ci = cls;
                    float v1 = __shfl_xor(v, 1); int c1 = __shfl_xor(ci, 1);
                    if (v1 > v || (v1 == v && c1 < ci)) { v = v1; ci = c1; }
                    float v2 = __shfl_xor(v, 2); int c2 = __shfl_xor(ci, 2);
                    if (v2 > v || (v2 == v && c2 < ci)) { v = v2; ci = c2; }
                    if (cls == 0) {
                        const int row = m * 16 + 4 * lq + r;
                        const int col = (w * 2 + ntl) ^ ((row & 7) << 2);
                        ((unsigned char*)(sC + row * 32 + col))[qq] = (unsigned char)ci;
                    }
                }
            }
    }
    __syncthreads();

    // ---------------- phase 5: decode (2-term MFMA, codes exact) --------------
    // wave w -> feat n-tile nt_d = w&7, token m-tile mp = w>>3
    const int nt_d = w & 7;
    const int mp   = w >> 3;
    f32x4 accd;
    #pragma unroll
    for (int r = 0; r < 4; ++r) accd[r] = 0.f;

    #pragma unroll
    for (int kt = 0; kt < 8; ++kt) {
        const unsigned short* bp = wsP + EBASE + (size_t)(kt * 8 + nt_d) * 1024 + l * 8;
        const s16x8 bh = *(const s16x8*)bp;
        const s16x8 bl = *(const s16x8*)(bp + 512);
        const int row = mp * 16 + lr;
        const int col = (kt * 4 + lq) ^ ((row & 7) << 2);
        const unsigned cw = sC[row * 32 + col];
        s16x8 a;
        #pragma unroll
        for (int q2 = 0; q2 < 4; ++q2) {
            const unsigned c = (cw >> (8 * q2)) & 0xffu;
            a[2 * q2]     = ((c & 1u) == 0u) ? (short)0x3F80 : (short)0;
            a[2 * q2 + 1] = (((c + 1u) & 2u) != 0u) ? (short)0x3F80 : (short)0;
        }
        accd = MFMA(a, bh, accd);
        accd = MFMA(a, bl, accd);
    }
    __syncthreads();

    // ---------------- phase 6: postscale norm + output ------------------------
    {
        float ps[4];
        #pragma unroll
        for (int r = 0; r < 4; ++r) {
            float s = accd[r] * accd[r];
            s += __shfl_xor(s, 1); s += __shfl_xor(s, 2);
            s += __shfl_xor(s, 4); s += __shfl_xor(s, 8);
            ps[r] = s;
        }
        if (lr == 0)
            *(float4*)(sPart + nt_d * 32 + mp * 16 + 4 * lq) =
                make_float4(ps[0], ps[1], ps[2], ps[3]);
    }
    __syncthreads();
    if (tid < 32) {
        float ssum = 0.f;
        #pragma unroll
        for (int g = 0; g < 8; ++g) ssum += sPart[g * 32 + tid];
        const float post = sqrtf(ssum);
        sFac[tid] = (1.0f / (post + F_EPS)) * (sPre[tid] + F_EPS);
    }
    __syncthreads();
    {
        const float sclv = scl[nt_d * 16 + lr] + F_EPS;
        #pragma unroll
        for (int r = 0; r < 4; ++r) {
            const int tokr = mp * 16 + 4 * lq + r;
            const float o = accd[r] * sFac[tokr] * sclv;
            out[(tok0 + tokr) * FEAT + nt_d * 16 + lr] = o;
        }
    }
}

extern "C" void kernel_launch(void* const* d_in, const int* in_sizes, int n_in,
                              void* d_out, int out_size, void* d_ws, size_t ws_size,
                              hipStream_t stream) {
    const float* x   = (const float*)d_in[0];
    const float* gu  = (const float*)d_in[1];
    const float* lnw = (const float*)d_in[2];
    const float* lnb = (const float*)d_in[3];
    const float* w1  = (const float*)d_in[4];
    const float* b1  = (const float*)d_in[5];
    const float* w2  = (const float*)d_in[6];
    const float* b2  = (const float*)d_in[7];
    const float* emb = (const float*)d_in[8];
    const float* scl = (const float*)d_in[9];
    float* out = (float*)d_out;

    unsigned short* wsP = (unsigned short*)d_ws;   // needs 2 MB

    hipLaunchKernelGGL(vc_pack, dim3(176), dim3(256), 0, stream, w1, w2, emb, wsP);

    const int ntok = in_sizes[0] / FEAT;           // 65536
    hipLaunchKernelGGL(vc_fused, dim3(ntok / TB), dim3(1024), 0, stream,
                       x, gu, lnw, lnb, b1, b2, scl, wsP, out);
}

// Round 8
// 398.233 us; speedup vs baseline: 1.1999x; 1.1999x over previous
//
#include <hip/hip_runtime.h>
#include <math.h>

#define FEAT  128
#define INTER 512
#define EMB   512
#define TB    32
#define SUBP  520   // u16 stride per kt-subplane of sXn (pad: +4-bank shift per kt)

typedef short s16x8 __attribute__((ext_vector_type(8)));
typedef short s16x4 __attribute__((ext_vector_type(4)));
typedef float f32x4 __attribute__((ext_vector_type(4)));

static constexpr float F_EPS    = 1e-6f;
static constexpr float F_LN_EPS = 1e-5f;

#define MFMA(a,b,c) __builtin_amdgcn_mfma_f32_16x16x32_bf16(a,b,c,0,0,0)

// u16-element offsets inside wsP (total 2 MB)
#define W1BASE 0                 // 128 frags * 1536 u16 (hi|mid|lo, 512 each)
#define W2BASE 196608            // 512 frags * 1536 u16
#define EBASE  983040            // 64  frags * 1024 u16 (hi|lo)

__device__ __forceinline__ unsigned short f2bf(float f) {
    union { float f; unsigned u; } v; v.f = f;
    unsigned r = v.u + 0x7FFFu + ((v.u >> 16) & 1u);
    return (unsigned short)(r >> 16);
}
__device__ __forceinline__ float bf2f(unsigned short h) {
    union { unsigned u; float f; } v; v.u = ((unsigned)h) << 16;
    return v.f;
}
__device__ __forceinline__ void split3(float x, unsigned short& h,
                                       unsigned short& m, unsigned short& l) {
    h = f2bf(x);
    float r1 = x - bf2f(h);
    m = f2bf(r1);
    l = f2bf(r1 - bf2f(m));
}
__device__ __forceinline__ float gelu_exact(float v) {
    return 0.5f * v * (1.0f + erff(v * 0.70710678118654752440f));
}

// Pack w1/w2 into 3-split, emb into 2-split MFMA B-fragments.
// Frag lane l holds B[k = kt*32 + 8*(l>>4) + i][n = nt*16 + (l&15)], i=0..7.
__global__ __launch_bounds__(256) void vc_pack(const float* __restrict__ w1,
                                               const float* __restrict__ w2,
                                               const float* __restrict__ emb,
                                               unsigned short* __restrict__ P) {
    int id = blockIdx.x * 256 + threadIdx.x;
    int fid = id >> 6, l = id & 63;
    if (fid >= 704) return;
    int lr = l & 15, lq = l >> 4;
    float v[8];
    size_t dst;
    int three = 1;
    if (fid < 128) {
        int kt = fid >> 5, nt = fid & 31;
        const float* s = w1 + (size_t)(nt * 16 + lr) * FEAT + kt * 32 + 8 * lq;
        #pragma unroll
        for (int i = 0; i < 8; ++i) v[i] = s[i];
        dst = W1BASE + (size_t)fid * 1536;
    } else if (fid < 640) {
        int f2 = fid - 128, kt = f2 >> 5, nt = f2 & 31;
        const float* s = w2 + (size_t)(nt * 16 + lr) * INTER + kt * 32 + 8 * lq;
        #pragma unroll
        for (int i = 0; i < 8; ++i) v[i] = s[i];
        dst = W2BASE + (size_t)f2 * 1536;
    } else {
        int f3 = fid - 640, kt = f3 >> 3, nt = f3 & 7;
        #pragma unroll
        for (int i = 0; i < 8; ++i)
            v[i] = emb[(size_t)(kt * 32 + 8 * lq + i) * FEAT + nt * 16 + lr];
        dst = EBASE + (size_t)f3 * 1024;
        three = 0;
    }
    s16x8 vh, vm, vl;
    #pragma unroll
    for (int i = 0; i < 8; ++i) {
        unsigned short a, b, c;
        split3(v[i], a, b, c);
        vh[i] = (short)a; vm[i] = (short)b; vl[i] = (short)c;
    }
    *(s16x8*)(P + dst + l * 8)       = vh;
    *(s16x8*)(P + dst + 512 + l * 8) = vm;   // for emb this is the lo plane
    if (three) *(s16x8*)(P + dst + 1024 + l * 8) = vl;
}

__global__ __launch_bounds__(1024, 8) void vc_fused(
    const float* __restrict__ x,   const float* __restrict__ gu,
    const float* __restrict__ lnw, const float* __restrict__ lnb,
    const float* __restrict__ b1,  const float* __restrict__ b2,
    const float* __restrict__ scl, const unsigned short* __restrict__ wsP,
    float* __restrict__ out)
{
    // LDS map, 79488 B total -> 2 blocks/CU, 8 waves/SIMD:
    //  [0,      24960)  xn 3 planes of [2mt*4kt (stride 520)][64 slot][8] u16
    //  [24960,  74112)  h  3 planes of [32][256] u16, 16B-granule XOR swizzle
    //  [74112,  78208)  sC [32][32] u32 (code bytes, col-swizzled)
    //  [78208,  79488)  sPre[32] | sPart[8][32] | sFac[32]
    __shared__ __align__(16) unsigned char smem[79488];
    unsigned short* sXn = (unsigned short*)smem;
    unsigned short* sH  = (unsigned short*)(smem + 24960);
    unsigned*       sC  = (unsigned*)(smem + 74112);
    float*          sPre  = (float*)(smem + 78208);
    float*          sPart = (float*)(smem + 78336);
    float*          sFac  = (float*)(smem + 79360);

    const int tid = threadIdx.x;
    const int w  = tid >> 6;           // wave 0..15
    const int l  = tid & 63;
    const int lr = l & 15, lq = l >> 4;
    const long tok0 = (long)blockIdx.x * TB;

    // ---------------- phase 0: scale, unit-norm, LayerNorm, 3-split frags ----
    // All 1024 threads: token t = tid>>5, feat quad q = tid&31 (4 feats each).
    {
        const int t = tid >> 5;        // token 0..31
        const int q = tid & 31;        // feat quad 0..31
        const float4 xv = *(const float4*)(x + (tok0 + t) * FEAT + q * 4);
        const float4 sv = *(const float4*)(scl + q * 4);
        float v[4];
        v[0] = xv.x / (sv.x + F_EPS); v[1] = xv.y / (sv.y + F_EPS);
        v[2] = xv.z / (sv.z + F_EPS); v[3] = xv.w / (sv.w + F_EPS);

        float ss = 0.f;
        #pragma unroll
        for (int k = 0; k < 4; ++k) ss += v[k] * v[k];
        ss += __shfl_xor(ss, 1);  ss += __shfl_xor(ss, 2);
        ss += __shfl_xor(ss, 4);  ss += __shfl_xor(ss, 8);
        ss += __shfl_xor(ss, 16);
        const float pre = sqrtf(ss);
        if (q == 0) sPre[t] = pre;
        const float ip = 1.0f / (pre + F_EPS);
        #pragma unroll
        for (int k = 0; k < 4; ++k) v[k] *= ip;

        float sm = 0.f;
        #pragma unroll
        for (int k = 0; k < 4; ++k) sm += v[k];
        sm += __shfl_xor(sm, 1);  sm += __shfl_xor(sm, 2);
        sm += __shfl_xor(sm, 4);  sm += __shfl_xor(sm, 8);
        sm += __shfl_xor(sm, 16);
        const float mu = sm * (1.0f / 128.0f);

        float vv = 0.f;
        #pragma unroll
        for (int k = 0; k < 4; ++k) { float d = v[k] - mu; vv += d * d; }
        vv += __shfl_xor(vv, 1);  vv += __shfl_xor(vv, 2);
        vv += __shfl_xor(vv, 4);  vv += __shfl_xor(vv, 8);
        vv += __shfl_xor(vv, 16);
        const float rst = 1.0f / sqrtf(vv * (1.0f / 128.0f) + F_LN_EPS);

        const float4 wv = *(const float4*)(lnw + q * 4);
        const float4 bv = *(const float4*)(lnb + q * 4);
        const float lw[4] = {wv.x, wv.y, wv.z, wv.w};
        const float lb[4] = {bv.x, bv.y, bv.z, bv.w};

        const int mt  = t >> 4;
        const int kt  = q >> 3;            // feat-octet kt
        const int sub = (q >> 1) & 3;
        const int hq  = q & 1;             // which half of the octet
        const size_t base = (size_t)(mt * 4 + kt) * SUBP
                          + (size_t)((t & 15) + 16 * sub) * 8 + hq * 4;
        s16x4 vh, vm, vlo;
        #pragma unroll
        for (int i = 0; i < 4; ++i) {
            const float xnv = (v[i] - mu) * rst * lw[i] + lb[i];
            unsigned short a, b, c;
            split3(xnv, a, b, c);
            vh[i] = (short)a; vm[i] = (short)b; vlo[i] = (short)c;
        }
        *(s16x4*)(sXn + base)        = vh;
        *(s16x4*)(sXn + 4160 + base) = vm;
        *(s16x4*)(sXn + 8320 + base) = vlo;
    }
    __syncthreads();

    f32x4 acc2[2][2];
    #pragma unroll
    for (int m = 0; m < 2; ++m)
        #pragma unroll
        for (int n = 0; n < 2; ++n)
            #pragma unroll
            for (int r = 0; r < 4; ++r) acc2[m][n][r] = 0.f;

    for (int half = 0; half < 2; ++half) {
        // -------- GEMM1 over n-half: 1 n-tile/wave, 6-term split-bf16 --------
        f32x4 acc1[2];
        #pragma unroll
        for (int m = 0; m < 2; ++m)
            #pragma unroll
            for (int r = 0; r < 4; ++r) acc1[m][r] = 0.f;

        #pragma unroll
        for (int kt = 0; kt < 4; ++kt) {
            s16x8 A[2][3];
            #pragma unroll
            for (int m = 0; m < 2; ++m) {
                const size_t base = (size_t)(m * 4 + kt) * SUBP + (size_t)l * 8;
                A[m][0] = *(const s16x8*)(sXn + base);
                A[m][1] = *(const s16x8*)(sXn + 4160 + base);
                A[m][2] = *(const s16x8*)(sXn + 8320 + base);
            }
            const int nt = half * 16 + w;
            const unsigned short* bp = wsP + W1BASE + (size_t)(kt * 32 + nt) * 1536 + l * 8;
            const s16x8 bh = *(const s16x8*)bp;
            const s16x8 bm = *(const s16x8*)(bp + 512);
            const s16x8 bl = *(const s16x8*)(bp + 1024);
            #pragma unroll
            for (int m = 0; m < 2; ++m) {
                f32x4 c = acc1[m];
                c = MFMA(A[m][1], bm, c);    // mid*mid   (~2^-18)
                c = MFMA(A[m][2], bh, c);    // lo*hi     (~2^-18)
                c = MFMA(A[m][0], bl, c);    // hi*lo     (~2^-18)
                c = MFMA(A[m][1], bh, c);    // mid*hi    (~2^-9)
                c = MFMA(A[m][0], bm, c);    // hi*mid    (~2^-9)
                c = MFMA(A[m][0], bh, c);    // hi*hi
                acc1[m] = c;
            }
        }

        // -------- bias + gelu, 3-split, write h half --------
        {
            const float b1v = b1[half * 256 + w * 16 + lr];
            #pragma unroll
            for (int m = 0; m < 2; ++m)
                #pragma unroll
                for (int r = 0; r < 4; ++r) {
                    const float h = gelu_exact(acc1[m][r] + b1v);
                    unsigned short hh, hm, hl;
                    split3(h, hh, hm, hl);
                    const int tokr = 4 * lq + r;
                    const int row  = m * 16 + tokr;
                    const int nl   = w * 16 + lr;                  // 0..255
                    const int gsw  = (nl >> 3) ^ (tokr & 7);
                    const size_t off = (size_t)row * 256 + gsw * 8 + (nl & 7);
                    sH[off]          = hh;
                    sH[8192 + off]   = hm;
                    sH[16384 + off]  = hl;
                }
        }
        __syncthreads();

        // -------- GEMM2 partial over k-half: 8 k-tiles, 2 n-tiles/wave --------
        for (int kk = 0; kk < 8; ++kk) {
            s16x8 A[2][3];
            #pragma unroll
            for (int m = 0; m < 2; ++m) {
                const int row = m * 16 + lr;
                const int gsw = (kk * 4 + lq) ^ (lr & 7);
                const size_t off = (size_t)row * 256 + (size_t)gsw * 8;
                A[m][0] = *(const s16x8*)(sH + off);
                A[m][1] = *(const s16x8*)(sH + 8192 + off);
                A[m][2] = *(const s16x8*)(sH + 16384 + off);
            }
            __builtin_amdgcn_s_setprio(1);
            #pragma unroll
            for (int ntl = 0; ntl < 2; ++ntl) {
                const int fid2 = (half * 8 + kk) * 32 + (w * 2 + ntl);
                const unsigned short* bp = wsP + W2BASE + (size_t)fid2 * 1536 + l * 8;
                const s16x8 bh = *(const s16x8*)bp;
                const s16x8 bm = *(const s16x8*)(bp + 512);
                const s16x8 bl = *(const s16x8*)(bp + 1024);
                #pragma unroll
                for (int m = 0; m < 2; ++m) {
                    f32x4 c = acc2[m][ntl];
                    c = MFMA(A[m][1], bm, c);
                    c = MFMA(A[m][2], bh, c);
                    c = MFMA(A[m][0], bl, c);
                    c = MFMA(A[m][1], bh, c);
                    c = MFMA(A[m][0], bm, c);
                    c = MFMA(A[m][0], bh, c);
                    acc2[m][ntl] = c;
                }
            }
            __builtin_amdgcn_s_setprio(0);
        }
        __syncthreads();
    }

    // ---------------- phase 4: bias + gumbel (libm logf) + quad argmax -------
    {
        float b2v[2];
        #pragma unroll
        for (int ntl = 0; ntl < 2; ++ntl) b2v[ntl] = b2[w * 32 + ntl * 16 + lr];
        const int qq  = lr >> 2;
        const int cls = l & 3;
        #pragma unroll
        for (int m = 0; m < 2; ++m)
            #pragma unroll
            for (int ntl = 0; ntl < 2; ++ntl) {
                #pragma unroll
                for (int r = 0; r < 4; ++r) {
                    const long tg = tok0 + m * 16 + 4 * lq + r;
                    const float u = gu[tg * 512 + w * 32 + ntl * 16 + lr];
                    float v = acc2[m][ntl][r] + b2v[ntl] - logf(-logf(u));
                    int   ci = cls;
                    float v1 = __shfl_xor(v, 1); int c1 = __shfl_xor(ci, 1);
                    if (v1 > v || (v1 == v && c1 < ci)) { v = v1; ci = c1; }
                    float v2 = __shfl_xor(v, 2); int c2 = __shfl_xor(ci, 2);
                    if (v2 > v || (v2 == v && c2 < ci)) { v = v2; ci = c2; }
                    if (cls == 0) {
                        const int row = m * 16 + 4 * lq + r;
                        const int col = (w * 2 + ntl) ^ ((row & 7) << 2);
                        ((unsigned char*)(sC + row * 32 + col))[qq] = (unsigned char)ci;
                    }
                }
            }
    }
    __syncthreads();

    // ---------------- phase 5: decode (2-term MFMA, codes exact) --------------
    // wave w -> feat n-tile nt_d = w&7, token m-tile mp = w>>3
    const int nt_d = w & 7;
    const int mp   = w >> 3;
    f32x4 accd;
    #pragma unroll
    for (int r = 0; r < 4; ++r) accd[r] = 0.f;

    #pragma unroll
    for (int kt = 0; kt < 8; ++kt) {
        const unsigned short* bp = wsP + EBASE + (size_t)(kt * 8 + nt_d) * 1024 + l * 8;
        const s16x8 bh = *(const s16x8*)bp;
        const s16x8 bl = *(const s16x8*)(bp + 512);
        const int row = mp * 16 + lr;
        const int col = (kt * 4 + lq) ^ ((row & 7) << 2);
        const unsigned cw = sC[row * 32 + col];
        s16x8 a;
        #pragma unroll
        for (int q2 = 0; q2 < 4; ++q2) {
            const unsigned c = (cw >> (8 * q2)) & 0xffu;
            a[2 * q2]     = ((c & 1u) == 0u) ? (short)0x3F80 : (short)0;
            a[2 * q2 + 1] = (((c + 1u) & 2u) != 0u) ? (short)0x3F80 : (short)0;
        }
        accd = MFMA(a, bh, accd);
        accd = MFMA(a, bl, accd);
    }
    __syncthreads();

    // ---------------- phase 6: postscale norm + output ------------------------
    {
        float ps[4];
        #pragma unroll
        for (int r = 0; r < 4; ++r) {
            float s = accd[r] * accd[r];
            s += __shfl_xor(s, 1); s += __shfl_xor(s, 2);
            s += __shfl_xor(s, 4); s += __shfl_xor(s, 8);
            ps[r] = s;
        }
        if (lr == 0)
            *(float4*)(sPart + nt_d * 32 + mp * 16 + 4 * lq) =
                make_float4(ps[0], ps[1], ps[2], ps[3]);
    }
    __syncthreads();
    if (tid < 32) {
        float ssum = 0.f;
        #pragma unroll
        for (int g = 0; g < 8; ++g) ssum += sPart[g * 32 + tid];
        const float post = sqrtf(ssum);
        sFac[tid] = (1.0f / (post + F_EPS)) * (sPre[tid] + F_EPS);
    }
    __syncthreads();
    {
        const float sclv = scl[nt_d * 16 + lr] + F_EPS;
        #pragma unroll
        for (int r = 0; r < 4; ++r) {
            const int tokr = mp * 16 + 4 * lq + r;
            const float o = accd[r] * sFac[tokr] * sclv;
            out[(tok0 + tokr) * FEAT + nt_d * 16 + lr] = o;
        }
    }
}

extern "C" void kernel_launch(void* const* d_in, const int* in_sizes, int n_in,
                              void* d_out, int out_size, void* d_ws, size_t ws_size,
                              hipStream_t stream) {
    const float* x   = (const float*)d_in[0];
    const float* gu  = (const float*)d_in[1];
    const float* lnw = (const float*)d_in[2];
    const float* lnb = (const float*)d_in[3];
    const float* w1  = (const float*)d_in[4];
    const float* b1  = (const float*)d_in[5];
    const float* w2  = (const float*)d_in[6];
    const float* b2  = (const float*)d_in[7];
    const float* emb = (const float*)d_in[8];
    const float* scl = (const float*)d_in[9];
    float* out = (float*)d_out;

    unsigned short* wsP = (unsigned short*)d_ws;   // needs 2 MB

    hipLaunchKernelGGL(vc_pack, dim3(176), dim3(256), 0, stream, w1, w2, emb, wsP);

    const int ntok = in_sizes[0] / FEAT;           // 65536
    hipLaunchKernelGGL(vc_fused, dim3(ntok / TB), dim3(1024), 0, stream,
                       x, gu, lnw, lnb, b1, b2, scl, wsP, out);
}

// Round 9
// 343.943 us; speedup vs baseline: 1.3894x; 1.1578x over previous
//
#include <hip/hip_runtime.h>
#include <math.h>

#define FEAT  128
#define INTER 512
#define EMB   512
#define TB    32

typedef short s16x8 __attribute__((ext_vector_type(8)));
typedef float f32x4 __attribute__((ext_vector_type(4)));

static constexpr float F_EPS    = 1e-6f;
static constexpr float F_LN_EPS = 1e-5f;

#define MFMA(a,b,c) __builtin_amdgcn_mfma_f32_16x16x32_bf16(a,b,c,0,0,0)

// u16-element offsets inside wsP (total 2 MB)
#define W1BASE 0                 // 128 frags * 1536 u16 (hi|mid|lo, 512 each)
#define W2BASE 196608            // 512 frags * 1536 u16
#define EBASE  983040            // 64  frags * 1024 u16 (hi|lo)

__device__ __forceinline__ unsigned short f2bf(float f) {
    union { float f; unsigned u; } v; v.f = f;
    unsigned r = v.u + 0x7FFFu + ((v.u >> 16) & 1u);
    return (unsigned short)(r >> 16);
}
__device__ __forceinline__ float bf2f(unsigned short h) {
    union { unsigned u; float f; } v; v.u = ((unsigned)h) << 16;
    return v.f;
}
__device__ __forceinline__ void split3(float x, unsigned short& h,
                                       unsigned short& m, unsigned short& l) {
    h = f2bf(x);
    float r1 = x - bf2f(h);
    m = f2bf(r1);
    l = f2bf(r1 - bf2f(m));
}
__device__ __forceinline__ float gelu_exact(float v) {
    return 0.5f * v * (1.0f + erff(v * 0.70710678118654752440f));
}

// Pack w1/w2 into 3-split, emb into 2-split MFMA B-fragments.
// Frag lane l holds B[k = kt*32 + 8*(l>>4) + i][n = nt*16 + (l&15)], i=0..7.
__global__ __launch_bounds__(256) void vc_pack(const float* __restrict__ w1,
                                               const float* __restrict__ w2,
                                               const float* __restrict__ emb,
                                               unsigned short* __restrict__ P) {
    int id = blockIdx.x * 256 + threadIdx.x;
    int fid = id >> 6, l = id & 63;
    if (fid >= 704) return;
    int lr = l & 15, lq = l >> 4;
    float v[8];
    size_t dst;
    int three = 1;
    if (fid < 128) {
        int kt = fid >> 5, nt = fid & 31;
        const float* s = w1 + (size_t)(nt * 16 + lr) * FEAT + kt * 32 + 8 * lq;
        #pragma unroll
        for (int i = 0; i < 8; ++i) v[i] = s[i];
        dst = W1BASE + (size_t)fid * 1536;
    } else if (fid < 640) {
        int f2 = fid - 128, kt = f2 >> 5, nt = f2 & 31;
        const float* s = w2 + (size_t)(nt * 16 + lr) * INTER + kt * 32 + 8 * lq;
        #pragma unroll
        for (int i = 0; i < 8; ++i) v[i] = s[i];
        dst = W2BASE + (size_t)f2 * 1536;
    } else {
        int f3 = fid - 640, kt = f3 >> 3, nt = f3 & 7;
        #pragma unroll
        for (int i = 0; i < 8; ++i)
            v[i] = emb[(size_t)(kt * 32 + 8 * lq + i) * FEAT + nt * 16 + lr];
        dst = EBASE + (size_t)f3 * 1024;
        three = 0;
    }
    s16x8 vh, vm, vl;
    #pragma unroll
    for (int i = 0; i < 8; ++i) {
        unsigned short a, b, c;
        split3(v[i], a, b, c);
        vh[i] = (short)a; vm[i] = (short)b; vl[i] = (short)c;
    }
    *(s16x8*)(P + dst + l * 8)       = vh;
    *(s16x8*)(P + dst + 512 + l * 8) = vm;   // for emb this is the lo plane
    if (three) *(s16x8*)(P + dst + 1024 + l * 8) = vl;
}

__global__ __launch_bounds__(1024, 8) void vc_fused(
    const float* __restrict__ x,   const float* __restrict__ gu,
    const float* __restrict__ lnw, const float* __restrict__ lnb,
    const float* __restrict__ b1,  const float* __restrict__ b2,
    const float* __restrict__ scl, const unsigned short* __restrict__ wsP,
    float* __restrict__ out)
{
    // LDS map, 79104 B total -> 2 blocks/CU, 8 waves/SIMD:
    //  [0,      24576)  xn 3 planes of [2mt][4kt][64lane][8] u16 (4096 u16 each)
    //  [24576,  73728)  h  3 planes of [32][256] u16, 16B-granule XOR swizzle
    //  [73728,  77824)  sC [32][32] u32 (code bytes, col-swizzled)
    //  [77824,  79104)  sPre[32] | sPart[8][32] | sFac[32]
    __shared__ __align__(16) unsigned char smem[79104];
    unsigned short* sXn = (unsigned short*)smem;
    unsigned short* sH  = (unsigned short*)(smem + 24576);
    unsigned*       sC  = (unsigned*)(smem + 73728);
    float*          sPre  = (float*)(smem + 77824);
    float*          sPart = (float*)(smem + 77952);
    float*          sFac  = (float*)(smem + 78976);

    const int tid = threadIdx.x;
    const int w  = tid >> 6;           // wave 0..15
    const int l  = tid & 63;
    const int lr = l & 15, lq = l >> 4;
    const long tok0 = (long)blockIdx.x * TB;

    // ---------------- phase 0: scale, unit-norm, LayerNorm, 3-split frags ----
    if (tid < 512) {                   // waves 0..7; branch is wave-uniform
        const int t = tid >> 4;        // token 0..31
        const int q = tid & 15;        // feat octet 0..15
        const float* xr = x + (tok0 + t) * FEAT + q * 8;
        float v[8];
        #pragma unroll
        for (int k = 0; k < 8; ++k) v[k] = xr[k] / (scl[q * 8 + k] + F_EPS);
        float ss = 0.f;
        #pragma unroll
        for (int k = 0; k < 8; ++k) ss += v[k] * v[k];
        ss += __shfl_xor(ss, 1); ss += __shfl_xor(ss, 2);
        ss += __shfl_xor(ss, 4); ss += __shfl_xor(ss, 8);
        const float pre = sqrtf(ss);
        if (q == 0) sPre[t] = pre;
        const float ip = 1.0f / (pre + F_EPS);
        #pragma unroll
        for (int k = 0; k < 8; ++k) v[k] *= ip;
        float sm = 0.f;
        #pragma unroll
        for (int k = 0; k < 8; ++k) sm += v[k];
        sm += __shfl_xor(sm, 1); sm += __shfl_xor(sm, 2);
        sm += __shfl_xor(sm, 4); sm += __shfl_xor(sm, 8);
        const float mu = sm * (1.0f / 128.0f);
        float vv = 0.f;
        #pragma unroll
        for (int k = 0; k < 8; ++k) { float d = v[k] - mu; vv += d * d; }
        vv += __shfl_xor(vv, 1); vv += __shfl_xor(vv, 2);
        vv += __shfl_xor(vv, 4); vv += __shfl_xor(vv, 8);
        const float rst = 1.0f / sqrtf(vv * (1.0f / 128.0f) + F_LN_EPS);

        const int mt  = t >> 4;
        const int kt  = q >> 2;
        const int sub = q & 3;
        const size_t base = ((size_t)(mt * 4 + kt) * 64 + (t & 15) + 16 * sub) * 8;
        s16x8 vh, vm, vlo;
        #pragma unroll
        for (int i = 0; i < 8; ++i) {
            const float xnv = (v[i] - mu) * rst * lnw[q * 8 + i] + lnb[q * 8 + i];
            unsigned short a, b, c;
            split3(xnv, a, b, c);
            vh[i] = (short)a; vm[i] = (short)b; vlo[i] = (short)c;
        }
        *(s16x8*)(sXn + base)        = vh;
        *(s16x8*)(sXn + 4096 + base) = vm;
        *(s16x8*)(sXn + 8192 + base) = vlo;
    }
    __syncthreads();

    f32x4 acc2[2][2];
    #pragma unroll
    for (int m = 0; m < 2; ++m)
        #pragma unroll
        for (int n = 0; n < 2; ++n)
            #pragma unroll
            for (int r = 0; r < 4; ++r) acc2[m][n][r] = 0.f;

    for (int half = 0; half < 2; ++half) {
        // -------- GEMM1 over n-half: 1 n-tile/wave, 6-term split-bf16 --------
        // Register diet: A loaded per-m (12 regs), B planes windowed (4 regs).
        // Term order per acc: hi*lo | mid*mid, hi*mid | lo*hi, mid*hi, hi*hi
        // (small terms first, hi*hi last).
        f32x4 acc1[2];
        #pragma unroll
        for (int m = 0; m < 2; ++m)
            #pragma unroll
            for (int r = 0; r < 4; ++r) acc1[m][r] = 0.f;

        #pragma unroll
        for (int kt = 0; kt < 4; ++kt) {
            const int nt = half * 16 + w;
            const unsigned short* bp =
                wsP + W1BASE + (size_t)(kt * 32 + nt) * 1536 + l * 8;
            #pragma unroll
            for (int m = 0; m < 2; ++m) {
                const size_t base = ((size_t)(m * 4 + kt) * 64 + l) * 8;
                const s16x8 A0 = *(const s16x8*)(sXn + base);
                const s16x8 A1 = *(const s16x8*)(sXn + 4096 + base);
                const s16x8 A2 = *(const s16x8*)(sXn + 8192 + base);
                f32x4 c = acc1[m];
                {
                    const s16x8 bl = *(const s16x8*)(bp + 1024);
                    c = MFMA(A0, bl, c);             // hi*lo   (~2^-18)
                }
                {
                    const s16x8 bm = *(const s16x8*)(bp + 512);
                    c = MFMA(A1, bm, c);             // mid*mid (~2^-18)
                    c = MFMA(A0, bm, c);             // hi*mid  (~2^-9)
                }
                {
                    const s16x8 bh = *(const s16x8*)bp;
                    c = MFMA(A2, bh, c);             // lo*hi   (~2^-18)
                    c = MFMA(A1, bh, c);             // mid*hi  (~2^-9)
                    c = MFMA(A0, bh, c);             // hi*hi
                }
                acc1[m] = c;
            }
        }

        // -------- bias + gelu, 3-split, write h half --------
        {
            const float b1v = b1[half * 256 + w * 16 + lr];
            #pragma unroll
            for (int m = 0; m < 2; ++m)
                #pragma unroll
                for (int r = 0; r < 4; ++r) {
                    const float h = gelu_exact(acc1[m][r] + b1v);
                    unsigned short hh, hm, hl;
                    split3(h, hh, hm, hl);
                    const int tokr = 4 * lq + r;
                    const int row  = m * 16 + tokr;
                    const int nl   = w * 16 + lr;                  // 0..255
                    const int gsw  = (nl >> 3) ^ (tokr & 7);
                    const size_t off = (size_t)row * 256 + gsw * 8 + (nl & 7);
                    sH[off]          = hh;
                    sH[8192 + off]   = hm;
                    sH[16384 + off]  = hl;
                }
        }
        __syncthreads();

        // -------- GEMM2 partial over k-half: 8 k-tiles, 2 n-tiles/wave --------
        // A[2][3] hoisted per kk (shared across ntl, no LDS re-reads);
        // B planes windowed (4 regs at a time).
        for (int kk = 0; kk < 8; ++kk) {
            s16x8 A0[2], A1[2], A2[2];
            #pragma unroll
            for (int m = 0; m < 2; ++m) {
                const int row = m * 16 + lr;
                const int gsw = (kk * 4 + lq) ^ (lr & 7);
                const size_t off = (size_t)row * 256 + (size_t)gsw * 8;
                A0[m] = *(const s16x8*)(sH + off);
                A1[m] = *(const s16x8*)(sH + 8192 + off);
                A2[m] = *(const s16x8*)(sH + 16384 + off);
            }
            #pragma unroll
            for (int ntl = 0; ntl < 2; ++ntl) {
                const int fid2 = (half * 8 + kk) * 32 + (w * 2 + ntl);
                const unsigned short* bp =
                    wsP + W2BASE + (size_t)fid2 * 1536 + l * 8;
                {
                    const s16x8 bl = *(const s16x8*)(bp + 1024);
                    acc2[0][ntl] = MFMA(A0[0], bl, acc2[0][ntl]);
                    acc2[1][ntl] = MFMA(A0[1], bl, acc2[1][ntl]);
                }
                {
                    const s16x8 bm = *(const s16x8*)(bp + 512);
                    acc2[0][ntl] = MFMA(A1[0], bm, acc2[0][ntl]);
                    acc2[1][ntl] = MFMA(A1[1], bm, acc2[1][ntl]);
                    acc2[0][ntl] = MFMA(A0[0], bm, acc2[0][ntl]);
                    acc2[1][ntl] = MFMA(A0[1], bm, acc2[1][ntl]);
                }
                {
                    const s16x8 bh = *(const s16x8*)bp;
                    acc2[0][ntl] = MFMA(A2[0], bh, acc2[0][ntl]);
                    acc2[1][ntl] = MFMA(A2[1], bh, acc2[1][ntl]);
                    acc2[0][ntl] = MFMA(A1[0], bh, acc2[0][ntl]);
                    acc2[1][ntl] = MFMA(A1[1], bh, acc2[1][ntl]);
                    acc2[0][ntl] = MFMA(A0[0], bh, acc2[0][ntl]);
                    acc2[1][ntl] = MFMA(A0[1], bh, acc2[1][ntl]);
                }
            }
        }
        __syncthreads();
    }

    // ---------------- phase 4: bias + gumbel (libm logf) + quad argmax -------
    {
        float b2v[2];
        #pragma unroll
        for (int ntl = 0; ntl < 2; ++ntl) b2v[ntl] = b2[w * 32 + ntl * 16 + lr];
        const int qq  = lr >> 2;
        const int cls = l & 3;
        #pragma unroll
        for (int m = 0; m < 2; ++m)
            #pragma unroll
            for (int ntl = 0; ntl < 2; ++ntl) {
                #pragma unroll
                for (int r = 0; r < 4; ++r) {
                    const long tg = tok0 + m * 16 + 4 * lq + r;
                    const float u = gu[tg * 512 + w * 32 + ntl * 16 + lr];
                    float v = acc2[m][ntl][r] + b2v[ntl] - logf(-logf(u));
                    int   ci = cls;
                    float v1 = __shfl_xor(v, 1); int c1 = __shfl_xor(ci, 1);
                    if (v1 > v || (v1 == v && c1 < ci)) { v = v1; ci = c1; }
                    float v2 = __shfl_xor(v, 2); int c2 = __shfl_xor(ci, 2);
                    if (v2 > v || (v2 == v && c2 < ci)) { v = v2; ci = c2; }
                    if (cls == 0) {
                        const int row = m * 16 + 4 * lq + r;
                        const int col = (w * 2 + ntl) ^ ((row & 7) << 2);
                        ((unsigned char*)(sC + row * 32 + col))[qq] = (unsigned char)ci;
                    }
                }
            }
    }
    __syncthreads();

    // ---------------- phase 5: decode (2-term MFMA, codes exact) --------------
    // wave w -> feat n-tile nt_d = w&7, token m-tile mp = w>>3
    const int nt_d = w & 7;
    const int mp   = w >> 3;
    f32x4 accd;
    #pragma unroll
    for (int r = 0; r < 4; ++r) accd[r] = 0.f;

    #pragma unroll
    for (int kt = 0; kt < 8; ++kt) {
        const unsigned short* bp = wsP + EBASE + (size_t)(kt * 8 + nt_d) * 1024 + l * 8;
        const int row = mp * 16 + lr;
        const int col = (kt * 4 + lq) ^ ((row & 7) << 2);
        const unsigned cw = sC[row * 32 + col];
        s16x8 a;
        #pragma unroll
        for (int q2 = 0; q2 < 4; ++q2) {
            const unsigned c = (cw >> (8 * q2)) & 0xffu;
            a[2 * q2]     = ((c & 1u) == 0u) ? (short)0x3F80 : (short)0;
            a[2 * q2 + 1] = (((c + 1u) & 2u) != 0u) ? (short)0x3F80 : (short)0;
        }
        {
            const s16x8 bh = *(const s16x8*)bp;
            accd = MFMA(a, bh, accd);
        }
        {
            const s16x8 bl = *(const s16x8*)(bp + 512);
            accd = MFMA(a, bl, accd);
        }
    }
    __syncthreads();

    // ---------------- phase 6: postscale norm + output ------------------------
    {
        float ps[4];
        #pragma unroll
        for (int r = 0; r < 4; ++r) {
            float s = accd[r] * accd[r];
            s += __shfl_xor(s, 1); s += __shfl_xor(s, 2);
            s += __shfl_xor(s, 4); s += __shfl_xor(s, 8);
            ps[r] = s;
        }
        if (lr == 0)
            *(float4*)(sPart + nt_d * 32 + mp * 16 + 4 * lq) =
                make_float4(ps[0], ps[1], ps[2], ps[3]);
    }
    __syncthreads();
    if (tid < 32) {
        float ssum = 0.f;
        #pragma unroll
        for (int g = 0; g < 8; ++g) ssum += sPart[g * 32 + tid];
        const float post = sqrtf(ssum);
        sFac[tid] = (1.0f / (post + F_EPS)) * (sPre[tid] + F_EPS);
    }
    __syncthreads();
    {
        const float sclv = scl[nt_d * 16 + lr] + F_EPS;
        #pragma unroll
        for (int r = 0; r < 4; ++r) {
            const int tokr = mp * 16 + 4 * lq + r;
            const float o = accd[r] * sFac[tokr] * sclv;
            out[(tok0 + tokr) * FEAT + nt_d * 16 + lr] = o;
        }
    }
}

extern "C" void kernel_launch(void* const* d_in, const int* in_sizes, int n_in,
                              void* d_out, int out_size, void* d_ws, size_t ws_size,
                              hipStream_t stream) {
    const float* x   = (const float*)d_in[0];
    const float* gu  = (const float*)d_in[1];
    const float* lnw = (const float*)d_in[2];
    const float* lnb = (const float*)d_in[3];
    const float* w1  = (const float*)d_in[4];
    const float* b1  = (const float*)d_in[5];
    const float* w2  = (const float*)d_in[6];
    const float* b2  = (const float*)d_in[7];
    const float* emb = (const float*)d_in[8];
    const float* scl = (const float*)d_in[9];
    float* out = (float*)d_out;

    unsigned short* wsP = (unsigned short*)d_ws;   // needs 2 MB

    hipLaunchKernelGGL(vc_pack, dim3(176), dim3(256), 0, stream, w1, w2, emb, wsP);

    const int ntok = in_sizes[0] / FEAT;           // 65536
    hipLaunchKernelGGL(vc_fused, dim3(ntok / TB), dim3(1024), 0, stream,
                       x, gu, lnw, lnb, b1, b2, scl, wsP, out);
}